// Round 1
// baseline (460.534 us; speedup 1.0000x reference)
//
#include <hip/hip_runtime.h>
#include <hip/hip_bf16.h>

typedef __attribute__((ext_vector_type(8))) short bf16x8;
typedef __attribute__((ext_vector_type(4))) float f32x4;

#define IN_DIM 128
#define OUT_DIM 256
#define KDIM 256

// ---------------- degree histogram ----------------
__global__ void k_hist(const int* __restrict__ edst, int* __restrict__ deg, int E) {
    int i = blockIdx.x * blockDim.x + threadIdx.x;
    int stride = gridDim.x * blockDim.x;
    for (; i < E; i += stride) atomicAdd(&deg[edst[i]], 1);
}

// ---------------- per-1024-chunk sums ----------------
__global__ void k_chunk_sum(const int* __restrict__ deg, int* __restrict__ bsum, int n) {
    __shared__ int sred[256];
    int base = blockIdx.x << 10;
    int s = 0;
    for (int j = threadIdx.x; j < 1024; j += 256) {
        int idx = base + j;
        if (idx < n) s += deg[idx];
    }
    sred[threadIdx.x] = s;
    __syncthreads();
    for (int off = 128; off > 0; off >>= 1) {
        if (threadIdx.x < off) sred[threadIdx.x] += sred[threadIdx.x + off];
        __syncthreads();
    }
    if (threadIdx.x == 0) bsum[blockIdx.x] = sred[0];
}

// ---------------- tiny serial scan of chunk sums ----------------
__global__ void k_scan_small(const int* __restrict__ bsum, int* __restrict__ boff,
                             int nb, int* __restrict__ offs_last) {
    if (threadIdx.x == 0 && blockIdx.x == 0) {
        int acc = 0;
        for (int i = 0; i < nb; i++) { boff[i] = acc; acc += bsum[i]; }
        offs_last[0] = acc;   // offs[N] = E
    }
}

// ---------------- final exclusive scan -> offs, cursor ----------------
__global__ void k_scan_final(const int* __restrict__ deg, const int* __restrict__ boff,
                             int* __restrict__ offs, int* __restrict__ cursor, int n) {
    __shared__ int sth[256];
    int base = blockIdx.x << 10;
    int t = threadIdx.x;
    int v[4]; int lsum = 0;
    int i0 = base + t * 4;
    for (int u = 0; u < 4; u++) {
        int idx = i0 + u;
        v[u] = (idx < n) ? deg[idx] : 0;
        lsum += v[u];
    }
    sth[t] = lsum;
    __syncthreads();
    for (int off = 1; off < 256; off <<= 1) {
        int add = (t >= off) ? sth[t - off] : 0;
        __syncthreads();
        sth[t] += add;
        __syncthreads();
    }
    int excl = sth[t] - lsum + boff[blockIdx.x];
    for (int u = 0; u < 4; u++) {
        int idx = i0 + u;
        if (idx < n) { offs[idx] = excl; cursor[idx] = excl; excl += v[u]; }
    }
}

// ---------------- CSR bucket fill ----------------
__global__ void k_fill(const int* __restrict__ esrc, const int* __restrict__ edst,
                       int* __restrict__ cursor, int* __restrict__ csr, int E) {
    int i = blockIdx.x * blockDim.x + threadIdx.x;
    int stride = gridDim.x * blockDim.x;
    for (; i < E; i += stride) {
        int d = edst[i];
        int p = atomicAdd(&cursor[d], 1);
        csr[p] = esrc[i];
    }
}

// ---------------- W -> bf16, transposed + XOR-swizzled (LDS byte order) ----------------
// wt layout: [half(2)][col_local(128)][k(256)] bf16, with byte-within-row XOR:
//   byte = half*65536 + cl*512 + ((2k) ^ ((cl&7)<<4))
__global__ void k_wprep(const float* __restrict__ W, __hip_bfloat16* __restrict__ wt) {
    int i = blockIdx.x * 256 + threadIdx.x;   // 65536 elements, i = k*256 + col
    int k = i >> 8, col = i & 255;
    int half = col >> 7, cl = col & 127;
    int byte = half * 65536 + cl * 512 + ((2 * k) ^ ((cl & 7) << 4));
    wt[byte >> 1] = __float2bfloat16(W[i]);
}

// ---------------- aggregate: one wave per node, write h = [bf16(x)|bf16(agg)] ----------------
__global__ void k_aggregate(const float* __restrict__ x, const int* __restrict__ offs,
                            const int* __restrict__ csr, __hip_bfloat16* __restrict__ h, int n) {
    int tid = threadIdx.x;
    int node = blockIdx.x * 4 + (tid >> 6);
    int lane = tid & 63;
    if (node >= n) return;
    int beg = offs[node], end = offs[node + 1];
    const float2* xf2 = (const float2*)x;   // 64 float2 per row
    float ax = 0.f, ay = 0.f;
    for (int j = beg; j < end; ++j) {
        int s = csr[j];
        float2 v = xf2[(size_t)s * 64 + lane];
        ax += v.x; ay += v.y;
    }
    float2 xs = xf2[(size_t)node * 64 + lane];
    int d = end - beg;
    float gx, gy;
    if (d > 0) {
        float inv = 1.0f / (float)d;
        gx = ax * inv; gy = ay * inv;
    } else {
        gx = xs.x; gy = xs.y;
    }
    __hip_bfloat162* h2 = (__hip_bfloat162*)(h + (size_t)node * 256);
    __hip_bfloat162 xp, gp;
    xp.x = __float2bfloat16(xs.x); xp.y = __float2bfloat16(xs.y);
    gp.x = __float2bfloat16(gx);   gp.y = __float2bfloat16(gy);
    h2[lane] = xp;
    h2[64 + lane] = gp;
}

// ---------------- GEMM: out = relu(h @ W + b), M=n, K=256, N=256 ----------------
// block = 256 thr (4 waves), BM=64 rows, BN=128 cols (blockIdx.x&1 selects half)
__global__ __launch_bounds__(256) void k_gemm(const __hip_bfloat16* __restrict__ h,
                                              const __hip_bfloat16* __restrict__ wt,
                                              const float* __restrict__ bias,
                                              float* __restrict__ out, int n) {
    __shared__ uint4 lds4[4096];   // 64KB: one W half in swizzled [col][k] order
    int tid = threadIdx.x;
    int half = blockIdx.x & 1;
    int tile = blockIdx.x >> 1;
    int row0 = tile * 64;

    // straight copy: ws already in final LDS byte order
    const uint4* src = (const uint4*)((const char*)wt + half * 65536);
    for (int i = tid; i < 4096; i += 256) lds4[i] = src[i];
    __syncthreads();

    int wave = tid >> 6, lane = tid & 63;
    int colb = lane & 15, kgrp = lane >> 4;
    int swz = (colb & 7) << 4;

    int wrow = row0 + wave * 16 + colb;           // A row this lane reads
    int arow = wrow < n ? wrow : (n - 1);
    const bf16x8* hrow = (const bf16x8*)(h + (size_t)arow * 256);  // 32 chunks of 8

    f32x4 acc[8];
#pragma unroll
    for (int nf = 0; nf < 8; nf++) acc[nf] = (f32x4){0.f, 0.f, 0.f, 0.f};

    const char* ldsb = (const char*)lds4;
#pragma unroll
    for (int ks = 0; ks < 8; ks++) {
        int k0 = kgrp * 8 + ks * 32;
        bf16x8 a = hrow[k0 >> 3];
        int kbyte = (2 * k0) ^ swz;
#pragma unroll
        for (int nf = 0; nf < 8; nf++) {
            int byteoff = (nf * 16 + colb) * 512 + kbyte;
            bf16x8 bfrag = *(const bf16x8*)(ldsb + byteoff);
            acc[nf] = __builtin_amdgcn_mfma_f32_16x16x32_bf16(a, bfrag, acc[nf], 0, 0, 0);
        }
    }

    int orow0 = row0 + wave * 16 + kgrp * 4;
#pragma unroll
    for (int nf = 0; nf < 8; nf++) {
        int col = half * 128 + nf * 16 + colb;
        float bv = bias[col];
#pragma unroll
        for (int i = 0; i < 4; i++) {
            int r = orow0 + i;
            if (r < n) {
                float v = acc[nf][i] + bv;
                out[(size_t)r * 256 + col] = v > 0.f ? v : 0.f;
            }
        }
    }
}

extern "C" void kernel_launch(void* const* d_in, const int* in_sizes, int n_in,
                              void* d_out, int out_size, void* d_ws, size_t ws_size,
                              hipStream_t stream) {
    const float* x    = (const float*)d_in[0];
    const int*   esrc = (const int*)d_in[1];
    const int*   edst = (const int*)d_in[2];
    const float* W    = (const float*)d_in[3];
    const float* bias = (const float*)d_in[4];
    float* out = (float*)d_out;

    int n = in_sizes[0] / IN_DIM;   // 100000
    int E = in_sizes[1];            // 1600000

    char* p = (char*)d_ws;
    auto alloc = [&](size_t bytes) {
        char* r = p;
        p += (bytes + 255) & ~(size_t)255;
        return r;
    };
    int* deg    = (int*)alloc((size_t)n * 4);
    int* offs   = (int*)alloc((size_t)(n + 1) * 4);
    int* cursor = (int*)alloc((size_t)n * 4);
    int* csr    = (int*)alloc((size_t)E * 4);
    int numB = (n + 1023) >> 10;
    int* bsum = (int*)alloc((size_t)numB * 4);
    int* boff = (int*)alloc((size_t)numB * 4);
    __hip_bfloat16* wt = (__hip_bfloat16*)alloc((size_t)65536 * 2);
    __hip_bfloat16* h  = (__hip_bfloat16*)alloc((size_t)n * 256 * 2);

    hipMemsetAsync(deg, 0, (size_t)n * 4, stream);
    k_hist<<<1024, 256, 0, stream>>>(edst, deg, E);
    k_chunk_sum<<<numB, 256, 0, stream>>>(deg, bsum, n);
    k_scan_small<<<1, 64, 0, stream>>>(bsum, boff, numB, offs + n);
    k_scan_final<<<numB, 256, 0, stream>>>(deg, boff, offs, cursor, n);
    k_fill<<<1024, 256, 0, stream>>>(esrc, edst, cursor, csr, E);
    k_wprep<<<256, 256, 0, stream>>>(W, wt);
    k_aggregate<<<(n + 3) / 4, 256, 0, stream>>>(x, offs, csr, h, n);
    k_gemm<<<((n + 63) / 64) * 2, 256, 0, stream>>>(h, wt, bias, out, n);
}

// Round 2
// 376.511 us; speedup vs baseline: 1.2232x; 1.2232x over previous
//
#include <hip/hip_runtime.h>
#include <hip/hip_bf16.h>

typedef __attribute__((ext_vector_type(8))) short bf16x8;
typedef __attribute__((ext_vector_type(4))) float f32x4;

#define IN_DIM 128
#define OUT_DIM 256

__device__ __forceinline__ float bf2f(short s) {
    unsigned int u = ((unsigned int)(unsigned short)s) << 16;
    return __builtin_bit_cast(float, u);
}
__device__ __forceinline__ short f2bf(float f) {
    __hip_bfloat16 t = __float2bfloat16(f);
    return __builtin_bit_cast(short, t);
}

// ---------------- fused: degree histogram + W prep + x->bf16 cast ----------------
// blocks [0,1024): hist; [1024,1280): wprep; [1280,1280+6250): xcast
__global__ void k_prep(const int* __restrict__ edst, int* __restrict__ deg, int E,
                       const float* __restrict__ x, __hip_bfloat16* __restrict__ xb, int nxelem,
                       const float* __restrict__ W, __hip_bfloat16* __restrict__ wt) {
    int b = blockIdx.x;
    int tid = threadIdx.x;
    if (b < 1024) {
        int i = b * 256 + tid;
        int stride = 1024 * 256;
        for (; i < E; i += stride) atomicAdd(&deg[edst[i]], 1);
    } else if (b < 1280) {
        // wt layout: [half(2)][col_local(128)][k(256)] bf16, byte XOR-swizzled
        int i = (b - 1024) * 256 + tid;   // i = k*256 + col, 65536 total
        int k = i >> 8, col = i & 255;
        int half = col >> 7, cl = col & 127;
        int byte = half * 65536 + cl * 512 + ((2 * k) ^ ((cl & 7) << 4));
        wt[byte >> 1] = __float2bfloat16(W[i]);
    } else {
        int i = (b - 1280) * 256 + tid;   // handles 8 elems
        size_t e0 = (size_t)i * 8;
        if (e0 < (size_t)nxelem) {
            const float4* xf4 = (const float4*)x;
            float4 v0 = xf4[i * 2], v1 = xf4[i * 2 + 1];
            bf16x8 o;
            o[0] = f2bf(v0.x); o[1] = f2bf(v0.y); o[2] = f2bf(v0.z); o[3] = f2bf(v0.w);
            o[4] = f2bf(v1.x); o[5] = f2bf(v1.y); o[6] = f2bf(v1.z); o[7] = f2bf(v1.w);
            *(bf16x8*)(xb + e0) = o;
        }
    }
}

// ---------------- per-1024-chunk sums ----------------
__global__ void k_chunk_sum(const int* __restrict__ deg, int* __restrict__ bsum, int n) {
    __shared__ int sred[256];
    int base = blockIdx.x << 10;
    int s = 0;
    for (int j = threadIdx.x; j < 1024; j += 256) {
        int idx = base + j;
        if (idx < n) s += deg[idx];
    }
    sred[threadIdx.x] = s;
    __syncthreads();
    for (int off = 128; off > 0; off >>= 1) {
        if (threadIdx.x < off) sred[threadIdx.x] += sred[threadIdx.x + off];
        __syncthreads();
    }
    if (threadIdx.x == 0) bsum[blockIdx.x] = sred[0];
}

__global__ void k_scan_small(const int* __restrict__ bsum, int* __restrict__ boff,
                             int nb, int* __restrict__ offs_last) {
    if (threadIdx.x == 0 && blockIdx.x == 0) {
        int acc = 0;
        for (int i = 0; i < nb; i++) { boff[i] = acc; acc += bsum[i]; }
        offs_last[0] = acc;
    }
}

__global__ void k_scan_final(const int* __restrict__ deg, const int* __restrict__ boff,
                             int* __restrict__ offs, int* __restrict__ cursor, int n) {
    __shared__ int sth[256];
    int base = blockIdx.x << 10;
    int t = threadIdx.x;
    int v[4]; int lsum = 0;
    int i0 = base + t * 4;
    for (int u = 0; u < 4; u++) {
        int idx = i0 + u;
        v[u] = (idx < n) ? deg[idx] : 0;
        lsum += v[u];
    }
    sth[t] = lsum;
    __syncthreads();
    for (int off = 1; off < 256; off <<= 1) {
        int add = (t >= off) ? sth[t - off] : 0;
        __syncthreads();
        sth[t] += add;
        __syncthreads();
    }
    int excl = sth[t] - lsum + boff[blockIdx.x];
    for (int u = 0; u < 4; u++) {
        int idx = i0 + u;
        if (idx < n) { offs[idx] = excl; cursor[idx] = excl; excl += v[u]; }
    }
}

__global__ void k_fill(const int* __restrict__ esrc, const int* __restrict__ edst,
                       int* __restrict__ cursor, int* __restrict__ csr, int E) {
    int i = blockIdx.x * blockDim.x + threadIdx.x;
    int stride = gridDim.x * blockDim.x;
    for (; i < E; i += stride) {
        int d = edst[i];
        int p = atomicAdd(&cursor[d], 1);
        csr[p] = esrc[i];
    }
}

// ---------------- aggregate: one wave per node, 4 edges in flight ----------------
// wave = 4 groups x 16 lanes; group g gathers edge beg+g, beg+g+4, ...
// each lane loads 16B (8 bf16) of the 256B row; cross-group shfl reduce at end.
__global__ void k_aggregate(const __hip_bfloat16* __restrict__ xb, const int* __restrict__ offs,
                            const int* __restrict__ csr, __hip_bfloat16* __restrict__ aggb, int n) {
    int tid = threadIdx.x;
    int node = blockIdx.x * 4 + (tid >> 6);
    if (node >= n) return;
    int lane = tid & 63;
    int g = lane >> 4;        // 0..3
    int l = lane & 15;        // chunk index within row
    int beg = offs[node], end = offs[node + 1];
    int d = end - beg;
    const bf16x8* xrows = (const bf16x8*)xb;   // 16 chunks per 128-elem row

    float acc[8];
#pragma unroll
    for (int u = 0; u < 8; u++) acc[u] = 0.f;

    for (int j = beg + g; j < end; j += 4) {
        int s = csr[j];
        bf16x8 v = xrows[(size_t)s * 16 + l];
#pragma unroll
        for (int u = 0; u < 8; u++) acc[u] += bf2f(v[u]);
    }

    // combine the 4 groups: lanes l, l+16, l+32, l+48 hold partials of same dims
#pragma unroll
    for (int u = 0; u < 8; u++) {
        acc[u] += __shfl_xor(acc[u], 16);
        acc[u] += __shfl_xor(acc[u], 32);
    }

    if (g == 0) {
        bf16x8 o;
        if (d > 0) {
            float inv = 1.0f / (float)d;
#pragma unroll
            for (int u = 0; u < 8; u++) o[u] = f2bf(acc[u] * inv);
        } else {
            o = xrows[(size_t)node * 16 + l];
        }
        *(bf16x8*)(aggb + (size_t)node * 128 + l * 8) = o;
    }
}

// ---------------- GEMM: out = relu([xb|aggb] @ W + b), M=n, K=256, N=256 ----------------
__global__ __launch_bounds__(256) void k_gemm(const __hip_bfloat16* __restrict__ xb,
                                              const __hip_bfloat16* __restrict__ aggb,
                                              const __hip_bfloat16* __restrict__ wt,
                                              const float* __restrict__ bias,
                                              float* __restrict__ out, int n) {
    __shared__ uint4 lds4[4096];   // 64KB: one W half, swizzled [col][k]
    int tid = threadIdx.x;
    int half = blockIdx.x & 1;
    int tile = blockIdx.x >> 1;
    int row0 = tile * 64;

    const uint4* src = (const uint4*)((const char*)wt + half * 65536);
    for (int i = tid; i < 4096; i += 256) lds4[i] = src[i];
    __syncthreads();

    int wave = tid >> 6, lane = tid & 63;
    int colb = lane & 15, kgrp = lane >> 4;
    int swz = (colb & 7) << 4;

    int wrow = row0 + wave * 16 + colb;
    int arow = wrow < n ? wrow : (n - 1);
    const bf16x8* xrow = (const bf16x8*)(xb + (size_t)arow * 128);    // 16 chunks
    const bf16x8* grow = (const bf16x8*)(aggb + (size_t)arow * 128);  // 16 chunks

    f32x4 acc[8];
#pragma unroll
    for (int nf = 0; nf < 8; nf++) acc[nf] = (f32x4){0.f, 0.f, 0.f, 0.f};

    const char* ldsb = (const char*)lds4;
#pragma unroll
    for (int ks = 0; ks < 8; ks++) {
        int k0 = kgrp * 8 + ks * 32;          // global k of this lane's 8 elems
        bf16x8 a = (ks < 4) ? xrow[kgrp + ks * 4] : grow[kgrp + (ks - 4) * 4];
        int kbyte = (2 * k0) ^ swz;
#pragma unroll
        for (int nf = 0; nf < 8; nf++) {
            int byteoff = (nf * 16 + colb) * 512 + kbyte;
            bf16x8 bfrag = *(const bf16x8*)(ldsb + byteoff);
            acc[nf] = __builtin_amdgcn_mfma_f32_16x16x32_bf16(a, bfrag, acc[nf], 0, 0, 0);
        }
    }

    int orow0 = row0 + wave * 16 + kgrp * 4;
#pragma unroll
    for (int nf = 0; nf < 8; nf++) {
        int col = half * 128 + nf * 16 + colb;
        float bv = bias[col];
#pragma unroll
        for (int i = 0; i < 4; i++) {
            int r = orow0 + i;
            if (r < n) {
                float v = acc[nf][i] + bv;
                out[(size_t)r * 256 + col] = v > 0.f ? v : 0.f;
            }
        }
    }
}

extern "C" void kernel_launch(void* const* d_in, const int* in_sizes, int n_in,
                              void* d_out, int out_size, void* d_ws, size_t ws_size,
                              hipStream_t stream) {
    const float* x    = (const float*)d_in[0];
    const int*   esrc = (const int*)d_in[1];
    const int*   edst = (const int*)d_in[2];
    const float* W    = (const float*)d_in[3];
    const float* bias = (const float*)d_in[4];
    float* out = (float*)d_out;

    int n = in_sizes[0] / IN_DIM;   // 100000
    int E = in_sizes[1];            // 1600000
    int nxelem = n * IN_DIM;        // 12.8M

    char* p = (char*)d_ws;
    auto alloc = [&](size_t bytes) {
        char* r = p;
        p += (bytes + 255) & ~(size_t)255;
        return r;
    };
    int* deg    = (int*)alloc((size_t)n * 4);
    int* offs   = (int*)alloc((size_t)(n + 1) * 4);
    int* cursor = (int*)alloc((size_t)n * 4);
    int* csr    = (int*)alloc((size_t)E * 4);
    int numB = (n + 1023) >> 10;
    int* bsum = (int*)alloc((size_t)numB * 4);
    int* boff = (int*)alloc((size_t)numB * 4);
    __hip_bfloat16* wt   = (__hip_bfloat16*)alloc((size_t)65536 * 2);
    __hip_bfloat16* xb   = (__hip_bfloat16*)alloc((size_t)nxelem * 2);
    __hip_bfloat16* aggb = (__hip_bfloat16*)alloc((size_t)nxelem * 2);

    int xcastB = (nxelem / 8 + 255) / 256;       // 6250
    hipMemsetAsync(deg, 0, (size_t)n * 4, stream);
    k_prep<<<1280 + xcastB, 256, 0, stream>>>(edst, deg, E, x, xb, nxelem, W, wt);
    k_chunk_sum<<<numB, 256, 0, stream>>>(deg, bsum, n);
    k_scan_small<<<1, 64, 0, stream>>>(bsum, boff, numB, offs + n);
    k_scan_final<<<numB, 256, 0, stream>>>(deg, boff, offs, cursor, n);
    k_fill<<<1024, 256, 0, stream>>>(esrc, edst, cursor, csr, E);
    k_aggregate<<<(n + 3) / 4, 256, 0, stream>>>(xb, offs, csr, aggb, n);
    k_gemm<<<((n + 63) / 64) * 2, 256, 0, stream>>>(xb, aggb, wt, bias, out, n);
}

// Round 3
// 235.472 us; speedup vs baseline: 1.9558x; 1.5990x over previous
//
#include <hip/hip_runtime.h>
#include <hip/hip_bf16.h>

typedef __attribute__((ext_vector_type(8))) short bf16x8;
typedef __attribute__((ext_vector_type(4))) float f32x4;

#define IN_DIM 128
#define OUT_DIM 256
#define CHUNK 4096

__device__ __forceinline__ float bf2f(short s) {
    unsigned int u = ((unsigned int)(unsigned short)s) << 16;
    return __builtin_bit_cast(float, u);
}
__device__ __forceinline__ short f2bf(float f) {
    __hip_bfloat16 t = __float2bfloat16(f);
    return __builtin_bit_cast(short, t);
}

// ---------------- fused: W prep + x->bf16 cast ----------------
// blocks [0,256): wprep; [256,256+6250): xcast
__global__ void k_prep(const float* __restrict__ x, __hip_bfloat16* __restrict__ xb, int nxelem,
                       const float* __restrict__ W, __hip_bfloat16* __restrict__ wt) {
    int b = blockIdx.x;
    int tid = threadIdx.x;
    if (b < 256) {
        // wt layout: [half(2)][col_local(128)][k(256)] bf16, byte XOR-swizzled
        int i = b * 256 + tid;   // i = k*256 + col, 65536 total
        int k = i >> 8, col = i & 255;
        int half = col >> 7, cl = col & 127;
        int byte = half * 65536 + cl * 512 + ((2 * k) ^ ((cl & 7) << 4));
        wt[byte >> 1] = __float2bfloat16(W[i]);
    } else {
        int i = (b - 256) * 256 + tid;   // handles 8 elems
        size_t e0 = (size_t)i * 8;
        if (e0 < (size_t)nxelem) {
            const float4* xf4 = (const float4*)x;
            float4 v0 = xf4[i * 2], v1 = xf4[i * 2 + 1];
            bf16x8 o;
            o[0] = f2bf(v0.x); o[1] = f2bf(v0.y); o[2] = f2bf(v0.z); o[3] = f2bf(v0.w);
            o[4] = f2bf(v1.x); o[5] = f2bf(v1.y); o[6] = f2bf(v1.z); o[7] = f2bf(v1.w);
            *(bf16x8*)(xb + e0) = o;
        }
    }
}

// ---------------- pass A1: per-bucket edge counts ----------------
__global__ void k_binA_count(const int* __restrict__ edst, int* __restrict__ gcnt,
                             int E, int NB) {
    __shared__ int cnt[512];
    int t = threadIdx.x;
    for (int b = t; b < NB; b += 256) cnt[b] = 0;
    __syncthreads();
    int e0 = blockIdx.x * CHUNK;
    int eend = min(e0 + CHUNK, E);
    for (int i = e0 + t; i < eend; i += 256) atomicAdd(&cnt[edst[i] >> 8], 1);
    __syncthreads();
    for (int b = t; b < NB; b += 256) if (cnt[b]) atomicAdd(&gcnt[b], cnt[b]);
}

// ---------------- tiny serial scan over buckets ----------------
__global__ void k_scan_nb(const int* __restrict__ gcnt, int* __restrict__ gbase,
                          int* __restrict__ gcur, int NB) {
    if (threadIdx.x == 0 && blockIdx.x == 0) {
        int acc = 0;
        for (int b = 0; b < NB; b++) { gbase[b] = acc; gcur[b] = acc; acc += gcnt[b]; }
        gbase[NB] = acc;
    }
}

// ---------------- pass A2: write packed (src<<8|dstlo) pairs in per-block runs ----------------
__global__ void k_binA_write(const int* __restrict__ esrc, const int* __restrict__ edst,
                             int* __restrict__ gcur, unsigned int* __restrict__ pairs,
                             int E, int NB) {
    __shared__ int cnt[512];
    __shared__ int base[512];
    int t = threadIdx.x;
    for (int b = t; b < NB; b += 256) cnt[b] = 0;
    __syncthreads();
    int e0 = blockIdx.x * CHUNK;
    int eend = min(e0 + CHUNK, E);
    for (int i = e0 + t; i < eend; i += 256) atomicAdd(&cnt[edst[i] >> 8], 1);
    __syncthreads();
    for (int b = t; b < NB; b += 256) {
        base[b] = cnt[b] ? atomicAdd(&gcur[b], cnt[b]) : 0;
        cnt[b] = 0;  // becomes local cursor
    }
    __syncthreads();
    for (int i = e0 + t; i < eend; i += 256) {
        int d = edst[i];
        int b = d >> 8;
        int idx = atomicAdd(&cnt[b], 1);
        pairs[base[b] + idx] = ((unsigned)esrc[i] << 8) | (unsigned)(d & 255);
    }
}

// ---------------- pass B: one block per bucket -> offs + csr (single-XCD window) ----------------
__global__ void k_binB(const unsigned int* __restrict__ pairs, const int* __restrict__ gbase,
                       int* __restrict__ offs, int* __restrict__ csr, int n) {
    __shared__ int cnt[256];
    __shared__ int tmp[256];
    int t = threadIdx.x;
    int b = blockIdx.x;
    int node0 = b << 8;
    cnt[t] = 0;
    __syncthreads();
    int beg = gbase[b], end = gbase[b + 1];
    for (int i = beg + t; i < end; i += 256) atomicAdd(&cnt[pairs[i] & 255], 1);
    __syncthreads();
    int v = cnt[t];
    tmp[t] = v;
    __syncthreads();
    for (int off = 1; off < 256; off <<= 1) {
        int add = (t >= off) ? tmp[t - off] : 0;
        __syncthreads();
        tmp[t] += add;
        __syncthreads();
    }
    int excl = tmp[t] - v;
    int node = node0 + t;
    if (node <= n) offs[node] = beg + excl;
    cnt[t] = beg + excl;   // global slot cursor for my node
    __syncthreads();
    for (int i = beg + t; i < end; i += 256) {
        unsigned p = pairs[i];
        int slot = atomicAdd(&cnt[p & 255], 1);
        csr[slot] = (int)(p >> 8);
    }
}

// ---------------- aggregate: one wave per node, 4 edges in flight ----------------
__global__ void k_aggregate(const __hip_bfloat16* __restrict__ xb, const int* __restrict__ offs,
                            const int* __restrict__ csr, __hip_bfloat16* __restrict__ aggb, int n) {
    int tid = threadIdx.x;
    int node = blockIdx.x * 4 + (tid >> 6);
    if (node >= n) return;
    int lane = tid & 63;
    int g = lane >> 4;        // 0..3
    int l = lane & 15;        // chunk index within row
    int beg = offs[node], end = offs[node + 1];
    int d = end - beg;
    const bf16x8* xrows = (const bf16x8*)xb;   // 16 chunks per 128-elem row

    float acc[8];
#pragma unroll
    for (int u = 0; u < 8; u++) acc[u] = 0.f;

    for (int j = beg + g; j < end; j += 4) {
        int s = csr[j];
        bf16x8 v = xrows[(size_t)s * 16 + l];
#pragma unroll
        for (int u = 0; u < 8; u++) acc[u] += bf2f(v[u]);
    }

#pragma unroll
    for (int u = 0; u < 8; u++) {
        acc[u] += __shfl_xor(acc[u], 16);
        acc[u] += __shfl_xor(acc[u], 32);
    }

    if (g == 0) {
        bf16x8 o;
        if (d > 0) {
            float inv = 1.0f / (float)d;
#pragma unroll
            for (int u = 0; u < 8; u++) o[u] = f2bf(acc[u] * inv);
        } else {
            o = xrows[(size_t)node * 16 + l];
        }
        *(bf16x8*)(aggb + (size_t)node * 128 + l * 8) = o;
    }
}

// ---------------- GEMM: out = relu([xb|aggb] @ W + b), M=n, K=256, N=256 ----------------
__global__ __launch_bounds__(256) void k_gemm(const __hip_bfloat16* __restrict__ xb,
                                              const __hip_bfloat16* __restrict__ aggb,
                                              const __hip_bfloat16* __restrict__ wt,
                                              const float* __restrict__ bias,
                                              float* __restrict__ out, int n) {
    __shared__ uint4 lds4[4096];   // 64KB: one W half, swizzled [col][k]
    int tid = threadIdx.x;
    int half = blockIdx.x & 1;
    int tile = blockIdx.x >> 1;
    int row0 = tile * 64;

    const uint4* src = (const uint4*)((const char*)wt + half * 65536);
    for (int i = tid; i < 4096; i += 256) lds4[i] = src[i];
    __syncthreads();

    int wave = tid >> 6, lane = tid & 63;
    int colb = lane & 15, kgrp = lane >> 4;
    int swz = (colb & 7) << 4;

    int wrow = row0 + wave * 16 + colb;
    int arow = wrow < n ? wrow : (n - 1);
    const bf16x8* xrow = (const bf16x8*)(xb + (size_t)arow * 128);
    const bf16x8* grow = (const bf16x8*)(aggb + (size_t)arow * 128);

    f32x4 acc[8];
#pragma unroll
    for (int nf = 0; nf < 8; nf++) acc[nf] = (f32x4){0.f, 0.f, 0.f, 0.f};

    const char* ldsb = (const char*)lds4;
#pragma unroll
    for (int ks = 0; ks < 8; ks++) {
        int k0 = kgrp * 8 + ks * 32;
        bf16x8 a = (ks < 4) ? xrow[kgrp + ks * 4] : grow[kgrp + (ks - 4) * 4];
        int kbyte = (2 * k0) ^ swz;
#pragma unroll
        for (int nf = 0; nf < 8; nf++) {
            int byteoff = (nf * 16 + colb) * 512 + kbyte;
            bf16x8 bfrag = *(const bf16x8*)(ldsb + byteoff);
            acc[nf] = __builtin_amdgcn_mfma_f32_16x16x32_bf16(a, bfrag, acc[nf], 0, 0, 0);
        }
    }

    int orow0 = row0 + wave * 16 + kgrp * 4;
#pragma unroll
    for (int nf = 0; nf < 8; nf++) {
        int col = half * 128 + nf * 16 + colb;
        float bv = bias[col];
#pragma unroll
        for (int i = 0; i < 4; i++) {
            int r = orow0 + i;
            if (r < n) {
                float v = acc[nf][i] + bv;
                out[(size_t)r * 256 + col] = v > 0.f ? v : 0.f;
            }
        }
    }
}

extern "C" void kernel_launch(void* const* d_in, const int* in_sizes, int n_in,
                              void* d_out, int out_size, void* d_ws, size_t ws_size,
                              hipStream_t stream) {
    const float* x    = (const float*)d_in[0];
    const int*   esrc = (const int*)d_in[1];
    const int*   edst = (const int*)d_in[2];
    const float* W    = (const float*)d_in[3];
    const float* bias = (const float*)d_in[4];
    float* out = (float*)d_out;

    int n = in_sizes[0] / IN_DIM;   // 100000
    int E = in_sizes[1];            // 1600000
    int nxelem = n * IN_DIM;        // 12.8M
    int NB = (n + 255) >> 8;        // 391 buckets of 256 nodes

    char* p = (char*)d_ws;
    auto alloc = [&](size_t bytes) {
        char* r = p;
        p += (bytes + 255) & ~(size_t)255;
        return r;
    };
    int* gcnt  = (int*)alloc((size_t)NB * 4);
    int* gbase = (int*)alloc((size_t)(NB + 1) * 4);
    int* gcur  = (int*)alloc((size_t)NB * 4);
    int* offs  = (int*)alloc((size_t)(n + 1) * 4);
    unsigned int* pairs = (unsigned int*)alloc((size_t)E * 4);
    int* csr   = (int*)alloc((size_t)E * 4);
    __hip_bfloat16* wt   = (__hip_bfloat16*)alloc((size_t)65536 * 2);
    __hip_bfloat16* xb   = (__hip_bfloat16*)alloc((size_t)nxelem * 2);
    __hip_bfloat16* aggb = (__hip_bfloat16*)alloc((size_t)nxelem * 2);

    int nEB = (E + CHUNK - 1) / CHUNK;           // 391
    int xcastB = (nxelem / 8 + 255) / 256;       // 6250

    hipMemsetAsync(gcnt, 0, (size_t)NB * 4, stream);
    k_binA_count<<<nEB, 256, 0, stream>>>(edst, gcnt, E, NB);
    k_scan_nb<<<1, 64, 0, stream>>>(gcnt, gbase, gcur, NB);
    k_binA_write<<<nEB, 256, 0, stream>>>(esrc, edst, gcur, pairs, E, NB);
    k_binB<<<NB, 256, 0, stream>>>(pairs, gbase, offs, csr, n);
    k_prep<<<256 + xcastB, 256, 0, stream>>>(x, xb, nxelem, W, wt);
    k_aggregate<<<(n + 3) / 4, 256, 0, stream>>>(xb, offs, csr, aggb, n);
    k_gemm<<<((n + 63) / 64) * 2, 256, 0, stream>>>(xb, aggb, wt, bias, out, n);
}

// Round 4
// 201.800 us; speedup vs baseline: 2.2821x; 1.1669x over previous
//
#include <hip/hip_runtime.h>
#include <hip/hip_bf16.h>

typedef __attribute__((ext_vector_type(8))) short bf16x8;
typedef __attribute__((ext_vector_type(4))) float f32x4;

#define IN_DIM 128
#define OUT_DIM 256
#define CHUNK 4096

__device__ __forceinline__ float bf2f(short s) {
    unsigned int u = ((unsigned int)(unsigned short)s) << 16;
    return __builtin_bit_cast(float, u);
}
__device__ __forceinline__ short f2bf(float f) {
    __hip_bfloat16 t = __float2bfloat16(f);
    return __builtin_bit_cast(short, t);
}

// ---------------- fused: W prep + x->bf16 cast ----------------
__global__ void k_prep(const float* __restrict__ x, __hip_bfloat16* __restrict__ xb, int nxelem,
                       const float* __restrict__ W, __hip_bfloat16* __restrict__ wt) {
    int b = blockIdx.x;
    int tid = threadIdx.x;
    if (b < 256) {
        // wt layout: [half(2)][col_local(128)][k(256)] bf16, byte XOR-swizzled
        int i = b * 256 + tid;   // i = k*256 + col
        int k = i >> 8, col = i & 255;
        int half = col >> 7, cl = col & 127;
        int byte = half * 65536 + cl * 512 + ((2 * k) ^ ((cl & 7) << 4));
        wt[byte >> 1] = __float2bfloat16(W[i]);
    } else {
        int i = (b - 256) * 256 + tid;   // 8 elems/thread
        size_t e0 = (size_t)i * 8;
        if (e0 < (size_t)nxelem) {
            const float4* xf4 = (const float4*)x;
            float4 v0 = xf4[i * 2], v1 = xf4[i * 2 + 1];
            bf16x8 o;
            o[0] = f2bf(v0.x); o[1] = f2bf(v0.y); o[2] = f2bf(v0.z); o[3] = f2bf(v0.w);
            o[4] = f2bf(v1.x); o[5] = f2bf(v1.y); o[6] = f2bf(v1.z); o[7] = f2bf(v1.w);
            *(bf16x8*)(xb + e0) = o;
        }
    }
}

// ---------------- pass A1: per-bucket edge counts ----------------
__global__ void k_binA_count(const int* __restrict__ edst, int* __restrict__ gcnt,
                             int E, int NB) {
    __shared__ int cnt[512];
    int t = threadIdx.x;
    for (int b = t; b < NB; b += 256) cnt[b] = 0;
    __syncthreads();
    int e0 = blockIdx.x * CHUNK;
    int eend = min(e0 + CHUNK, E);
    for (int i = e0 + t; i < eend; i += 256) atomicAdd(&cnt[edst[i] >> 8], 1);
    __syncthreads();
    for (int b = t; b < NB; b += 256) if (cnt[b]) atomicAdd(&gcnt[b], cnt[b]);
}

__global__ void k_scan_nb(const int* __restrict__ gcnt, int* __restrict__ gbase,
                          int* __restrict__ gcur, int NB) {
    if (threadIdx.x == 0 && blockIdx.x == 0) {
        int acc = 0;
        for (int b = 0; b < NB; b++) { gbase[b] = acc; gcur[b] = acc; acc += gcnt[b]; }
        gbase[NB] = acc;
    }
}

// ---------------- pass A2: packed (src<<8|dstlo) pairs in per-block runs ----------------
__global__ void k_binA_write(const int* __restrict__ esrc, const int* __restrict__ edst,
                             int* __restrict__ gcur, unsigned int* __restrict__ pairs,
                             int E, int NB) {
    __shared__ int cnt[512];
    __shared__ int base[512];
    int t = threadIdx.x;
    for (int b = t; b < NB; b += 256) cnt[b] = 0;
    __syncthreads();
    int e0 = blockIdx.x * CHUNK;
    int eend = min(e0 + CHUNK, E);
    for (int i = e0 + t; i < eend; i += 256) atomicAdd(&cnt[edst[i] >> 8], 1);
    __syncthreads();
    for (int b = t; b < NB; b += 256) {
        base[b] = cnt[b] ? atomicAdd(&gcur[b], cnt[b]) : 0;
        cnt[b] = 0;
    }
    __syncthreads();
    for (int i = e0 + t; i < eend; i += 256) {
        int d = edst[i];
        int b = d >> 8;
        int idx = atomicAdd(&cnt[b], 1);
        pairs[base[b] + idx] = ((unsigned)esrc[i] << 8) | (unsigned)(d & 255);
    }
}

// ---------------- pass B: one block per bucket -> offs + csr ----------------
__global__ void k_binB(const unsigned int* __restrict__ pairs, const int* __restrict__ gbase,
                       int* __restrict__ offs, int* __restrict__ csr, int n) {
    __shared__ int cnt[256];
    __shared__ int tmp[256];
    int t = threadIdx.x;
    int b = blockIdx.x;
    int node0 = b << 8;
    cnt[t] = 0;
    __syncthreads();
    int beg = gbase[b], end = gbase[b + 1];
    for (int i = beg + t; i < end; i += 256) atomicAdd(&cnt[pairs[i] & 255], 1);
    __syncthreads();
    int v = cnt[t];
    tmp[t] = v;
    __syncthreads();
    for (int off = 1; off < 256; off <<= 1) {
        int add = (t >= off) ? tmp[t - off] : 0;
        __syncthreads();
        tmp[t] += add;
        __syncthreads();
    }
    int excl = tmp[t] - v;
    int node = node0 + t;
    if (node <= n) offs[node] = beg + excl;
    cnt[t] = beg + excl;
    __syncthreads();
    for (int i = beg + t; i < end; i += 256) {
        unsigned p = pairs[i];
        int slot = atomicAdd(&cnt[p & 255], 1);
        csr[slot] = (int)(p >> 8);
    }
}

// ---------------- aggregate: one wave per node, 8 edges in flight ----------------
__global__ void k_aggregate(const __hip_bfloat16* __restrict__ xb, const int* __restrict__ offs,
                            const int* __restrict__ csr, __hip_bfloat16* __restrict__ aggb, int n) {
    int tid = threadIdx.x;
    int node = blockIdx.x * 4 + (tid >> 6);
    if (node >= n) return;
    int lane = tid & 63;
    int g = lane >> 4;        // 0..3
    int l = lane & 15;        // 16B chunk within row
    int beg = offs[node], end = offs[node + 1];
    int d = end - beg;
    const bf16x8* xrows = (const bf16x8*)xb;

    float a0[8], a1[8];
#pragma unroll
    for (int u = 0; u < 8; u++) { a0[u] = 0.f; a1[u] = 0.f; }

    int j = beg + g;
    for (; j + 4 < end; j += 8) {
        int s0 = csr[j];
        int s1 = csr[j + 4];
        bf16x8 v0 = xrows[(size_t)s0 * 16 + l];
        bf16x8 v1 = xrows[(size_t)s1 * 16 + l];
#pragma unroll
        for (int u = 0; u < 8; u++) { a0[u] += bf2f(v0[u]); a1[u] += bf2f(v1[u]); }
    }
    if (j < end) {
        int s0 = csr[j];
        bf16x8 v0 = xrows[(size_t)s0 * 16 + l];
#pragma unroll
        for (int u = 0; u < 8; u++) a0[u] += bf2f(v0[u]);
    }

#pragma unroll
    for (int u = 0; u < 8; u++) {
        float s = a0[u] + a1[u];
        s += __shfl_xor(s, 16);
        s += __shfl_xor(s, 32);
        a0[u] = s;
    }

    if (g == 0) {
        bf16x8 o;
        if (d > 0) {
            float inv = 1.0f / (float)d;
#pragma unroll
            for (int u = 0; u < 8; u++) o[u] = f2bf(a0[u] * inv);
        } else {
            o = xrows[(size_t)node * 16 + l];
        }
        *(bf16x8*)(aggb + (size_t)node * 128 + l * 8) = o;
    }
}

// ---------------- GEMM: out = relu([xb|aggb] @ W + b), BM=256, BN=128 ----------------
// 4 waves; wave w owns rows row0+w*64..+63 (4 M-frags).
// Swapped-operand MFMA: mfma(Wfrag, hfrag, acc) -> lane holds 4 consecutive out cols.
__global__ __launch_bounds__(256, 2) void k_gemm(const __hip_bfloat16* __restrict__ xb,
                                                 const __hip_bfloat16* __restrict__ aggb,
                                                 const __hip_bfloat16* __restrict__ wt,
                                                 const float* __restrict__ bias,
                                                 float* __restrict__ out, int n) {
    __shared__ uint4 lds4[4096];   // 64KB: one W half, swizzled [col][k]
    int tid = threadIdx.x;
    int half = blockIdx.x & 1;
    int tile = blockIdx.x >> 1;
    int row0 = tile * 256;

    const uint4* src = (const uint4*)((const char*)wt + half * 65536);
    for (int i = tid; i < 4096; i += 256) lds4[i] = src[i];
    __syncthreads();

    int wave = tid >> 6, lane = tid & 63;
    int colb = lane & 15, kgrp = lane >> 4;
    int swz = (colb & 7) << 4;
    int wrow0 = row0 + wave * 64;

    const bf16x8* hx[4];
    const bf16x8* hg[4];
#pragma unroll
    for (int m = 0; m < 4; m++) {
        int r = wrow0 + m * 16 + colb;
        int ar = r < n ? r : (n - 1);
        hx[m] = (const bf16x8*)(xb + (size_t)ar * 128);
        hg[m] = (const bf16x8*)(aggb + (size_t)ar * 128);
    }

    f32x4 acc[4][8];
#pragma unroll
    for (int m = 0; m < 4; m++)
#pragma unroll
        for (int nf = 0; nf < 8; nf++) acc[m][nf] = (f32x4){0.f, 0.f, 0.f, 0.f};

    const char* ldsb = (const char*)lds4;
#pragma unroll
    for (int ks = 0; ks < 8; ks++) {
        bf16x8 a[4];
#pragma unroll
        for (int m = 0; m < 4; m++)
            a[m] = (ks < 4) ? hx[m][kgrp + ks * 4] : hg[m][kgrp + (ks - 4) * 4];
        int kbyte = (kgrp * 16 + ks * 64) ^ swz;
#pragma unroll
        for (int nf = 0; nf < 8; nf++) {
            bf16x8 bfrag = *(const bf16x8*)(ldsb + (nf * 16 + colb) * 512 + kbyte);
#pragma unroll
            for (int m = 0; m < 4; m++)
                acc[m][nf] = __builtin_amdgcn_mfma_f32_16x16x32_bf16(bfrag, a[m], acc[m][nf], 0, 0, 0);
        }
    }

    // D layout (swapped): out row = wrow0 + m*16 + colb ; out col = half*128 + nf*16 + kgrp*4 + i
#pragma unroll
    for (int m = 0; m < 4; m++) {
        int r = wrow0 + m * 16 + colb;
        if (r < n) {
            float* orow = out + (size_t)r * 256 + half * 128;
#pragma unroll
            for (int nf = 0; nf < 8; nf++) {
                int c0 = nf * 16 + kgrp * 4;
                float4 bv = *(const float4*)(bias + half * 128 + c0);
                float4 v;
                v.x = acc[m][nf][0] + bv.x;
                v.y = acc[m][nf][1] + bv.y;
                v.z = acc[m][nf][2] + bv.z;
                v.w = acc[m][nf][3] + bv.w;
                v.x = v.x > 0.f ? v.x : 0.f;
                v.y = v.y > 0.f ? v.y : 0.f;
                v.z = v.z > 0.f ? v.z : 0.f;
                v.w = v.w > 0.f ? v.w : 0.f;
                *(float4*)(orow + c0) = v;
            }
        }
    }
}

extern "C" void kernel_launch(void* const* d_in, const int* in_sizes, int n_in,
                              void* d_out, int out_size, void* d_ws, size_t ws_size,
                              hipStream_t stream) {
    const float* x    = (const float*)d_in[0];
    const int*   esrc = (const int*)d_in[1];
    const int*   edst = (const int*)d_in[2];
    const float* W    = (const float*)d_in[3];
    const float* bias = (const float*)d_in[4];
    float* out = (float*)d_out;

    int n = in_sizes[0] / IN_DIM;   // 100000
    int E = in_sizes[1];            // 1600000
    int nxelem = n * IN_DIM;
    int NB = (n + 255) >> 8;        // 391

    char* p = (char*)d_ws;
    auto alloc = [&](size_t bytes) {
        char* r = p;
        p += (bytes + 255) & ~(size_t)255;
        return r;
    };
    int* gcnt  = (int*)alloc((size_t)NB * 4);
    int* gbase = (int*)alloc((size_t)(NB + 1) * 4);
    int* gcur  = (int*)alloc((size_t)NB * 4);
    int* offs  = (int*)alloc((size_t)(n + 1) * 4);
    unsigned int* pairs = (unsigned int*)alloc((size_t)E * 4);
    int* csr   = (int*)alloc((size_t)E * 4);
    __hip_bfloat16* wt   = (__hip_bfloat16*)alloc((size_t)65536 * 2);
    __hip_bfloat16* xb   = (__hip_bfloat16*)alloc((size_t)nxelem * 2);
    __hip_bfloat16* aggb = (__hip_bfloat16*)alloc((size_t)nxelem * 2);

    int nEB = (E + CHUNK - 1) / CHUNK;
    int xcastB = (nxelem / 8 + 255) / 256;

    hipMemsetAsync(gcnt, 0, (size_t)NB * 4, stream);
    k_binA_count<<<nEB, 256, 0, stream>>>(edst, gcnt, E, NB);
    k_scan_nb<<<1, 64, 0, stream>>>(gcnt, gbase, gcur, NB);
    k_binA_write<<<nEB, 256, 0, stream>>>(esrc, edst, gcur, pairs, E, NB);
    k_binB<<<NB, 256, 0, stream>>>(pairs, gbase, offs, csr, n);
    k_prep<<<256 + xcastB, 256, 0, stream>>>(x, xb, nxelem, W, wt);
    k_aggregate<<<(n + 3) / 4, 256, 0, stream>>>(xb, offs, csr, aggb, n);
    k_gemm<<<((n + 255) / 256) * 2, 256, 0, stream>>>(xb, aggb, wt, bias, out, n);
}

// Round 5
// 177.771 us; speedup vs baseline: 2.5906x; 1.1352x over previous
//
#include <hip/hip_runtime.h>
#include <hip/hip_bf16.h>

typedef __attribute__((ext_vector_type(8))) short bf16x8;
typedef __attribute__((ext_vector_type(4))) float f32x4;
typedef __attribute__((ext_vector_type(2))) float f32x2;

#define IN_DIM 128
#define OUT_DIM 256
#define CHUNK 4096

__device__ __forceinline__ float bf2f(short s) {
    unsigned int u = ((unsigned int)(unsigned short)s) << 16;
    return __builtin_bit_cast(float, u);
}
__device__ __forceinline__ short f2bf(float f) {
    __hip_bfloat16 t = __float2bfloat16(f);
    return __builtin_bit_cast(short, t);
}

// unpack u32 (2 bf16) -> f32x2 and accumulate (v_pk_add_f32 friendly)
__device__ __forceinline__ void accum8(f32x2 a[4], uint4 v) {
    const unsigned* u = (const unsigned*)&v;
#pragma unroll
    for (int i = 0; i < 4; i++) {
        f32x2 t;
        t.x = __builtin_bit_cast(float, u[i] << 16);
        t.y = __builtin_bit_cast(float, u[i] & 0xFFFF0000u);
        a[i] += t;
    }
}

// ---------------- fused: bucket count + W prep + x->bf16 cast ----------------
// blocks [0,nEB): bucket-count; [nEB,nEB+256): wprep; rest: xcast
__global__ void k_prep(const int* __restrict__ edst, int* __restrict__ gcnt, int E,
                       int nEB, int NB,
                       const float* __restrict__ x, __hip_bfloat16* __restrict__ xb, int nxelem,
                       const float* __restrict__ W, __hip_bfloat16* __restrict__ wt) {
    __shared__ int cnt[512];
    int b = blockIdx.x;
    int tid = threadIdx.x;
    if (b < nEB) {
        for (int i = tid; i < NB; i += 256) cnt[i] = 0;
        __syncthreads();
        int e0 = b * CHUNK;
        int eend = min(e0 + CHUNK, E);
        for (int i = e0 + tid; i < eend; i += 256) atomicAdd(&cnt[edst[i] >> 8], 1);
        __syncthreads();
        for (int i = tid; i < NB; i += 256) if (cnt[i]) atomicAdd(&gcnt[i], cnt[i]);
    } else if (b < nEB + 256) {
        // wt layout: [half(2)][col_local(128)][k(256)] bf16, byte XOR-swizzled
        int i = (b - nEB) * 256 + tid;   // i = k*256 + col
        int k = i >> 8, col = i & 255;
        int half = col >> 7, cl = col & 127;
        int byte = half * 65536 + cl * 512 + ((2 * k) ^ ((cl & 7) << 4));
        wt[byte >> 1] = __float2bfloat16(W[i]);
    } else {
        int i = (b - nEB - 256) * 256 + tid;   // 8 elems/thread
        size_t e0 = (size_t)i * 8;
        if (e0 < (size_t)nxelem) {
            const float4* xf4 = (const float4*)x;
            float4 v0 = xf4[i * 2], v1 = xf4[i * 2 + 1];
            bf16x8 o;
            o[0] = f2bf(v0.x); o[1] = f2bf(v0.y); o[2] = f2bf(v0.z); o[3] = f2bf(v0.w);
            o[4] = f2bf(v1.x); o[5] = f2bf(v1.y); o[6] = f2bf(v1.z); o[7] = f2bf(v1.w);
            *(bf16x8*)(xb + e0) = o;
        }
    }
}

// ---------------- one-block parallel scan over buckets ----------------
__global__ void k_scan_nb(const int* __restrict__ gcnt, int* __restrict__ gbase,
                          int* __restrict__ gcur, int NB) {
    __shared__ int tmp[512];
    int t = threadIdx.x;
    int v = (t < NB) ? gcnt[t] : 0;
    tmp[t] = v;
    __syncthreads();
    for (int off = 1; off < 512; off <<= 1) {
        int add = (t >= off) ? tmp[t - off] : 0;
        __syncthreads();
        tmp[t] += add;
        __syncthreads();
    }
    int excl = tmp[t] - v;
    if (t < NB) { gbase[t] = excl; gcur[t] = excl; }
    if (t == 511) gbase[NB] = tmp[511];
}

// ---------------- pass A2: packed (src<<8|dstlo) pairs in per-block runs ----------------
__global__ void k_binA_write(const int* __restrict__ esrc, const int* __restrict__ edst,
                             int* __restrict__ gcur, unsigned int* __restrict__ pairs,
                             int E, int NB) {
    __shared__ int cnt[512];
    __shared__ int base[512];
    int t = threadIdx.x;
    for (int b = t; b < NB; b += 256) cnt[b] = 0;
    __syncthreads();
    int e0 = blockIdx.x * CHUNK;
    int eend = min(e0 + CHUNK, E);
    for (int i = e0 + t; i < eend; i += 256) atomicAdd(&cnt[edst[i] >> 8], 1);
    __syncthreads();
    for (int b = t; b < NB; b += 256) {
        base[b] = cnt[b] ? atomicAdd(&gcur[b], cnt[b]) : 0;
        cnt[b] = 0;
    }
    __syncthreads();
    for (int i = e0 + t; i < eend; i += 256) {
        int d = edst[i];
        int b = d >> 8;
        int idx = atomicAdd(&cnt[b], 1);
        pairs[base[b] + idx] = ((unsigned)esrc[i] << 8) | (unsigned)(d & 255);
    }
}

// ---------------- pass B: one block per bucket -> offs + csr ----------------
__global__ void k_binB(const unsigned int* __restrict__ pairs, const int* __restrict__ gbase,
                       int* __restrict__ offs, int* __restrict__ csr, int n) {
    __shared__ int cnt[256];
    __shared__ int tmp[256];
    int t = threadIdx.x;
    int b = blockIdx.x;
    int node0 = b << 8;
    cnt[t] = 0;
    __syncthreads();
    int beg = gbase[b], end = gbase[b + 1];
    for (int i = beg + t; i < end; i += 256) atomicAdd(&cnt[pairs[i] & 255], 1);
    __syncthreads();
    int v = cnt[t];
    tmp[t] = v;
    __syncthreads();
    for (int off = 1; off < 256; off <<= 1) {
        int add = (t >= off) ? tmp[t - off] : 0;
        __syncthreads();
        tmp[t] += add;
        __syncthreads();
    }
    int excl = tmp[t] - v;
    int node = node0 + t;
    if (node <= n) offs[node] = beg + excl;
    cnt[t] = beg + excl;
    __syncthreads();
    for (int i = beg + t; i < end; i += 256) {
        unsigned p = pairs[i];
        int slot = atomicAdd(&cnt[p & 255], 1);
        csr[slot] = (int)(p >> 8);
    }
}

// ---------------- aggregate: one wave per node, 16 edges in flight per wave ----------------
// 4 groups x 16 lanes; each group streams 4 loads deep, single packed accumulator.
__global__ void k_aggregate(const __hip_bfloat16* __restrict__ xb, const int* __restrict__ offs,
                            const int* __restrict__ csr, __hip_bfloat16* __restrict__ aggb, int n) {
    int tid = threadIdx.x;
    int node = blockIdx.x * 4 + (tid >> 6);
    if (node >= n) return;
    int lane = tid & 63;
    int g = lane >> 4;        // 0..3
    int l = lane & 15;        // 16B chunk within row
    int beg = offs[node], end = offs[node + 1];
    int d = end - beg;
    const uint4* xrows = (const uint4*)xb;   // 16 uint4 per 128-elem row

    f32x2 acc[4];
#pragma unroll
    for (int i = 0; i < 4; i++) acc[i] = (f32x2){0.f, 0.f};

    int j = beg + g;
    // 4 loads in flight per group
    for (; j + 12 < end; j += 16) {
        int s0 = csr[j], s1 = csr[j + 4], s2 = csr[j + 8], s3 = csr[j + 12];
        uint4 v0 = xrows[(size_t)s0 * 16 + l];
        uint4 v1 = xrows[(size_t)s1 * 16 + l];
        uint4 v2 = xrows[(size_t)s2 * 16 + l];
        uint4 v3 = xrows[(size_t)s3 * 16 + l];
        accum8(acc, v0); accum8(acc, v1); accum8(acc, v2); accum8(acc, v3);
    }
    for (; j < end; j += 4) {
        uint4 v = xrows[(size_t)csr[j] * 16 + l];
        accum8(acc, v);
    }

    float r[8];
#pragma unroll
    for (int i = 0; i < 4; i++) { r[2 * i] = acc[i].x; r[2 * i + 1] = acc[i].y; }
#pragma unroll
    for (int u = 0; u < 8; u++) {
        r[u] += __shfl_xor(r[u], 16);
        r[u] += __shfl_xor(r[u], 32);
    }

    if (g == 0) {
        bf16x8 o;
        if (d > 0) {
            float inv = 1.0f / (float)d;
#pragma unroll
            for (int u = 0; u < 8; u++) o[u] = f2bf(r[u] * inv);
        } else {
            o = *(const bf16x8*)(xrows + (size_t)node * 16 + l);
        }
        *(bf16x8*)(aggb + (size_t)node * 128 + l * 8) = o;
    }
}

// ---------------- GEMM: out = relu([xb|aggb] @ W + b), BM=256, BN=128 ----------------
__global__ __launch_bounds__(256, 2) void k_gemm(const __hip_bfloat16* __restrict__ xb,
                                                 const __hip_bfloat16* __restrict__ aggb,
                                                 const __hip_bfloat16* __restrict__ wt,
                                                 const float* __restrict__ bias,
                                                 float* __restrict__ out, int n) {
    __shared__ uint4 lds4[4096];   // 64KB: one W half, swizzled [col][k]
    int tid = threadIdx.x;
    int half = blockIdx.x & 1;
    int tile = blockIdx.x >> 1;
    int row0 = tile * 256;

    const uint4* src = (const uint4*)((const char*)wt + half * 65536);
    for (int i = tid; i < 4096; i += 256) lds4[i] = src[i];
    __syncthreads();

    int wave = tid >> 6, lane = tid & 63;
    int colb = lane & 15, kgrp = lane >> 4;
    int swz = (colb & 7) << 4;
    int wrow0 = row0 + wave * 64;

    const bf16x8* hx[4];
    const bf16x8* hg[4];
#pragma unroll
    for (int m = 0; m < 4; m++) {
        int r = wrow0 + m * 16 + colb;
        int ar = r < n ? r : (n - 1);
        hx[m] = (const bf16x8*)(xb + (size_t)ar * 128);
        hg[m] = (const bf16x8*)(aggb + (size_t)ar * 128);
    }

    f32x4 acc[4][8];
#pragma unroll
    for (int m = 0; m < 4; m++)
#pragma unroll
        for (int nf = 0; nf < 8; nf++) acc[m][nf] = (f32x4){0.f, 0.f, 0.f, 0.f};

    const char* ldsb = (const char*)lds4;
#pragma unroll
    for (int ks = 0; ks < 8; ks++) {
        bf16x8 a[4];
#pragma unroll
        for (int m = 0; m < 4; m++)
            a[m] = (ks < 4) ? hx[m][kgrp + ks * 4] : hg[m][kgrp + (ks - 4) * 4];
        int kbyte = (kgrp * 16 + ks * 64) ^ swz;
#pragma unroll
        for (int nf = 0; nf < 8; nf++) {
            bf16x8 bfrag = *(const bf16x8*)(ldsb + (nf * 16 + colb) * 512 + kbyte);
#pragma unroll
            for (int m = 0; m < 4; m++)
                acc[m][nf] = __builtin_amdgcn_mfma_f32_16x16x32_bf16(bfrag, a[m], acc[m][nf], 0, 0, 0);
        }
    }

    // out row = wrow0 + m*16 + colb ; out col = half*128 + nf*16 + kgrp*4 + i
#pragma unroll
    for (int m = 0; m < 4; m++) {
        int r = wrow0 + m * 16 + colb;
        if (r < n) {
            float* orow = out + (size_t)r * 256 + half * 128;
#pragma unroll
            for (int nf = 0; nf < 8; nf++) {
                int c0 = nf * 16 + kgrp * 4;
                float4 bv = *(const float4*)(bias + half * 128 + c0);
                float4 v;
                v.x = acc[m][nf][0] + bv.x;
                v.y = acc[m][nf][1] + bv.y;
                v.z = acc[m][nf][2] + bv.z;
                v.w = acc[m][nf][3] + bv.w;
                v.x = v.x > 0.f ? v.x : 0.f;
                v.y = v.y > 0.f ? v.y : 0.f;
                v.z = v.z > 0.f ? v.z : 0.f;
                v.w = v.w > 0.f ? v.w : 0.f;
                *(float4*)(orow + c0) = v;
            }
        }
    }
}

extern "C" void kernel_launch(void* const* d_in, const int* in_sizes, int n_in,
                              void* d_out, int out_size, void* d_ws, size_t ws_size,
                              hipStream_t stream) {
    const float* x    = (const float*)d_in[0];
    const int*   esrc = (const int*)d_in[1];
    const int*   edst = (const int*)d_in[2];
    const float* W    = (const float*)d_in[3];
    const float* bias = (const float*)d_in[4];
    float* out = (float*)d_out;

    int n = in_sizes[0] / IN_DIM;   // 100000
    int E = in_sizes[1];            // 1600000
    int nxelem = n * IN_DIM;
    int NB = (n + 255) >> 8;        // 391

    char* p = (char*)d_ws;
    auto alloc = [&](size_t bytes) {
        char* r = p;
        p += (bytes + 255) & ~(size_t)255;
        return r;
    };
    int* gcnt  = (int*)alloc((size_t)NB * 4);
    int* gbase = (int*)alloc((size_t)(NB + 1) * 4);
    int* gcur  = (int*)alloc((size_t)NB * 4);
    int* offs  = (int*)alloc((size_t)(n + 1) * 4);
    unsigned int* pairs = (unsigned int*)alloc((size_t)E * 4);
    int* csr   = (int*)alloc((size_t)E * 4);
    __hip_bfloat16* wt   = (__hip_bfloat16*)alloc((size_t)65536 * 2);
    __hip_bfloat16* xb   = (__hip_bfloat16*)alloc((size_t)nxelem * 2);
    __hip_bfloat16* aggb = (__hip_bfloat16*)alloc((size_t)nxelem * 2);

    int nEB = (E + CHUNK - 1) / CHUNK;           // 391
    int xcastB = (nxelem / 8 + 255) / 256;       // 6250

    hipMemsetAsync(gcnt, 0, (size_t)NB * 4, stream);
    k_prep<<<nEB + 256 + xcastB, 256, 0, stream>>>(edst, gcnt, E, nEB, NB,
                                                   x, xb, nxelem, W, wt);
    k_scan_nb<<<1, 512, 0, stream>>>(gcnt, gbase, gcur, NB);
    k_binA_write<<<nEB, 256, 0, stream>>>(esrc, edst, gcur, pairs, E, NB);
    k_binB<<<NB, 256, 0, stream>>>(pairs, gbase, offs, csr, n);
    k_aggregate<<<(n + 3) / 4, 256, 0, stream>>>(xb, offs, csr, aggb, n);
    k_gemm<<<((n + 255) / 256) * 2, 256, 0, stream>>>(xb, aggb, wt, bias, out, n);
}